// Round 8
// baseline (555.987 us; speedup 1.0000x reference)
//
#include <hip/hip_runtime.h>
#include <stdint.h>

#define H      160
#define G3     480
#define NCH    10
#define TCH    20
#define CC     200
#define NCLS   16
#define NLAYERS 160
#define NLEVELS 161
#define NSEQ   (NLEVELS * NCH * H)
#define NT     512
#define NPAIR  64
#define NLAYB  (2*NPAIR)          // 128 layer blocks
#define GRID   (NLAYB + NCH + 1)  // 139 blocks, all co-resident on 256 CUs

// Canary: quiet-NaN bit pattern. GRU hidden states are never NaN, so any
// legit value differs. Compare the BIT PATTERN (NaN float-compare is false).
#define CANARY 0x7fbadbadu

typedef float f4 __attribute__((ext_vector_type(4)));

// Two mirrored handoff buffers:
//  g_seq : agent-scope (LLC) — always written, always correct.
//  g_fast: plain write-back stores — visible to same-XCD consumers via the
//          shared per-XCD L2 at ~200cy instead of the ~900cy LLC round trip.
// Consumers poll 4x sc0(g_fast) : 1x agent(g_seq); progress never depends on
// block->XCD placement (the agent probe is the guaranteed path).
__device__ float g_seq[NSEQ];    // [161][10][160] level/chunk/feature
__device__ float g_fast[NSEQ];

__device__ __forceinline__ float sigm(float x){ return 1.0f / (1.0f + expf(-x)); }

__device__ __forceinline__ void stf(float* p, float v){      // agent (LLC)
  __hip_atomic_store(p, v, __ATOMIC_RELAXED, __HIP_MEMORY_SCOPE_AGENT);
}
__device__ __forceinline__ void stw(float* p, float v){      // plain (local L2)
  __hip_atomic_store(p, v, __ATOMIC_RELAXED, __HIP_MEMORY_SCOPE_WORKGROUP);
}
__device__ __forceinline__ float ldf(float* p){              // agent (LLC)
  return __hip_atomic_load(p, __ATOMIC_RELAXED, __HIP_MEMORY_SCOPE_AGENT);
}
// L1-bypass load: reads the (per-XCD shared) L2 fresh each call.
__device__ __forceinline__ float ld_sc0(const float* p){
  float v;
  asm volatile("global_load_dword %0, %1, off sc0\n\t"
               "s_waitcnt vmcnt(0)"
               : "=v"(v) : "v"(p) : "memory");
  return v;
}
// Dual-path poll: fast same-XCD L2 probes with a guaranteed LLC fallback.
__device__ __forceinline__ float poll2(const float* fast, float* slow){
  while (true){
#pragma unroll
    for (int i = 0; i < 4; ++i){
      float v = ld_sc0(fast);
      if (__float_as_uint(v) != CANARY) return v;
    }
    float v = ldf(slow);
    if (__float_as_uint(v) != CANARY) return v;
  }
}

// 80-MAC dot with weights in quad-column-major LDS: w[k*stride] for k=0..19.
// Lane-to-lane stride = 1 float4 -> conflict-free reads.
__device__ __forceinline__ float dotq20(const float4* __restrict__ w, int stride,
                                        const float* __restrict__ v){
  float a0 = 0.f, a1 = 0.f;
#pragma unroll
  for (int k = 0; k < 20; k += 2){
    float4 wa = w[k*stride], wb = w[(k+1)*stride];
    f4 va = *(const f4*)(v + 4*k), vb = *(const f4*)(v + 4*k + 4);
    a0 = fmaf(wa.x, va.x, a0); a0 = fmaf(wa.y, va.y, a0);
    a0 = fmaf(wa.z, va.z, a0); a0 = fmaf(wa.w, va.w, a0);
    a1 = fmaf(wb.x, vb.x, a1); a1 = fmaf(wb.y, vb.y, a1);
    a1 = fmaf(wb.z, vb.z, a1); a1 = fmaf(wb.w, vb.w, a1);
  }
  return a0 + a1;
}

// ---- 80 columns of whh pinned in 20 named VGPR quads (80 VGPRs) -----------
#define WH_DECL  f4 w00,w01,w02,w03,w04,w05,w06,w07,w08,w09, \
                    w10,w11,w12,w13,w14,w15,w16,w17,w18,w19
#define WH_LOAD(SRC) do { const f4* ws_ = (const f4*)(SRC); \
  w00=ws_[0]; w01=ws_[1]; w02=ws_[2]; w03=ws_[3]; w04=ws_[4]; \
  w05=ws_[5]; w06=ws_[6]; w07=ws_[7]; w08=ws_[8]; w09=ws_[9]; \
  w10=ws_[10];w11=ws_[11];w12=ws_[12];w13=ws_[13];w14=ws_[14]; \
  w15=ws_[15];w16=ws_[16];w17=ws_[17];w18=ws_[18];w19=ws_[19]; } while(0)
#define WH_PIN() asm volatile("" : \
  "+v"(w00),"+v"(w01),"+v"(w02),"+v"(w03),"+v"(w04), \
  "+v"(w05),"+v"(w06),"+v"(w07),"+v"(w08),"+v"(w09), \
  "+v"(w10),"+v"(w11),"+v"(w12),"+v"(w13),"+v"(w14), \
  "+v"(w15),"+v"(w16),"+v"(w17),"+v"(w18),"+v"(w19))
#define MACP(WA,WB,OFF) do { \
  f4 va_ = *(const f4*)(v_ + (OFF));  f4 vb_ = *(const f4*)(v_ + (OFF) + 4); \
  a0_=fmaf(WA.x,va_.x,a0_); a0_=fmaf(WA.y,va_.y,a0_); \
  a0_=fmaf(WA.z,va_.z,a0_); a0_=fmaf(WA.w,va_.w,a0_); \
  a1_=fmaf(WB.x,vb_.x,a1_); a1_=fmaf(WB.y,vb_.y,a1_); \
  a1_=fmaf(WB.z,vb_.z,a1_); a1_=fmaf(WB.w,vb_.w,a1_); } while(0)
#define WH_DOT80(RES, VBASE) do { const float* v_ = (VBASE); \
  float a0_=0.f, a1_=0.f; \
  MACP(w00,w01,0);  MACP(w02,w03,8);  MACP(w04,w05,16); MACP(w06,w07,24); \
  MACP(w08,w09,32); MACP(w10,w11,40); MACP(w12,w13,48); MACP(w14,w15,56); \
  MACP(w16,w17,64); MACP(w18,w19,72); (RES) = a0_ + a1_; } while(0)
// ---------------------------------------------------------------------------

extern "C" __global__ void poison_kernel(){
  int i = threadIdx.x + blockIdx.x * blockDim.x;
  float c = __uint_as_float(CANARY);
  if (i < NSEQ){ stf(&g_seq[i], c); stf(&g_fast[i], c); }
}

extern "C" __global__ __launch_bounds__(NT, 1)
void spectral_wave(
  const float* __restrict__ x,
  const float* __restrict__ b_wih, const float* __restrict__ b_whh,
  const float* __restrict__ b_bih, const float* __restrict__ b_bhh,
  const float* __restrict__ g_wih, const float* __restrict__ g_whh,
  const float* __restrict__ g_bih, const float* __restrict__ g_bhh,
  const float* __restrict__ g3_wih, const float* __restrict__ g3_whh,
  const float* __restrict__ g3_bih, const float* __restrict__ g3_bhh,
  const float* __restrict__ bn_gamma, const float* __restrict__ bn_beta,
  const float* __restrict__ bn_mean,  const float* __restrict__ bn_var,
  const float* __restrict__ fc_w, const float* __restrict__ fc_b,
  const float* __restrict__ reg_w, const float* __restrict__ reg_b,
  float* __restrict__ out)
{
  const int tid = threadIdx.x;
  const int bid = blockIdx.x;

  // XCD-aware remap (empirically XCD = bid % 8 on MI355X): logical index
  // lm = xcd*16 + slot puts 8 consecutive layer-PAIRS per XCD, so 7/8 of the
  // layer->layer hops and ALL sibling exchanges are intra-XCD (L2 fast path).
  // Performance heuristic only — correctness never depends on it (poll2).
  int lm;
  if (bid < NLAYB){ int xcd = bid & 7, slot = bid >> 3; lm = xcd*16 + slot; }
  else lm = bid;

  // 9640 float4 = 154.2 KB weight LDS + 5.1 KB buffers = 159.4 KB (<160 KiB)
  // Pitch 241/481: staging WRITES get lane-to-lane bank step 4 (conflict-free
  // minimal 8-phase); reads keep lane stride 1 float4 (conflict-free).
  __shared__ float4 s_w4[9640];
  __shared__ __align__(16) float s_buf[1280];

  if (lm < NLAYB) {
    // ======== layer-half block: pair p, role (A: h 0..79 / B: h 80..159) ====
    const int p = lm >> 1, role = lm & 1, hbase = role * 80;
    const int nlay = (p < 32) ? 3 : 2;     // layers p, p+64, (p+128 if p<32)
    const bool act = tid < 480;
    const int j    = tid % 240;            // local pre-row 0..239
    const int hf   = (tid / 240) & 1;      // K half (valid under act)
    const int c0   = 80 * hf;
    const int band = j / 80;               // 0=r rows,1=z rows,2=n rows
    const int grow = band*160 + (j % 80) + hbase;  // global pre-row 0..479

    float* sx   = s_buf;        // [160] input chunk
    float* sh   = s_buf + 160;  // [160] recurrent h (own half + polled half)
    float* swp  = s_buf + 320;  // [2][240] per-half partials
    float* shp2 = s_buf + 800;  // [2][80]  band-2 h-partials (hn)

    for (int li = 0; li < nlay; ++li){
      const int l = p + 64*li;

      // stage wih half (rows grow(j), all 160 cols) quad-column-major:
      // s_w4[qi*241 + jj] = wih[grow(jj)][4qi..4qi+3]
      {
        const float4* src = (const float4*)(g3_wih + (size_t)l*G3*H);
        for (int it = 0; it < 19; ++it){
          int fidx = it*NT + tid;            // jj*40 + qi
          if (fidx < 9600){
            int jj = fidx / 40, qi = fidx - jj*40;
            int gr = (jj/80)*160 + (jj%80) + hbase;
            s_w4[qi*241 + jj] = src[gr*40 + qi];
          }
        }
      }
      WH_DECL;
      float bihj = 0.f, bhhj = 0.f;
      if (act){
        WH_LOAD(g3_whh + ((size_t)l*G3 + grow)*H + c0);
        WH_PIN();
        if (hf == 0){ bihj = g3_bih[l*G3 + grow]; bhhj = g3_bhh[l*G3 + grow]; }
      }
      if (tid < 160) sh[tid] = 0.f;
      __syncthreads();

      float* seq_in   = g_seq  + (size_t)l     * NCH * H;
      float* seq_out  = g_seq  + (size_t)(l+1) * NCH * H;
      float* fast_in  = g_fast + (size_t)l     * NCH * H;
      float* fast_out = g_fast + (size_t)(l+1) * NCH * H;

      for (int t = 0; t < NCH; ++t){
        if (tid < 160){
          sx[tid] = poll2(&fast_in[t*H + tid], &seq_in[t*H + tid]);
        } else if (tid < 240 && t > 0){
          int oi = (role == 0 ? 80 : 0) + (tid - 160);   // sibling h half
          sh[oi] = poll2(&fast_out[(t-1)*H + oi], &seq_out[(t-1)*H + oi]);
        }
        __syncthreads();
        if (act){
          float s_w = dotq20(&s_w4[hf*4820 + j], 241, sx + c0) + bihj;
          float s_h; WH_DOT80(s_h, sh + c0); s_h += bhhj;
          if (band < 2) swp[hf*240 + j] = s_w + s_h;
          else { swp[hf*240 + j] = s_w; shp2[hf*80 + (j-160)] = s_h; }
        }
        __syncthreads();
        if (tid < 80){
          int i = tid, hi = hbase + i;
          float pr = swp[i]       + swp[240 + i];
          float pz = swp[80 + i]  + swp[320 + i];
          float xn = swp[160 + i] + swp[400 + i];
          float hn = shp2[i]      + shp2[80 + i];
          float rg = sigm(pr);
          float z  = sigm(pz);
          float n  = tanhf(xn + rg * hn);
          float h  = (1.f - z) * n + z * sh[hi];
          sh[hi] = h;
          stw(&fast_out[t*H + hi], h);  // same-XCD fast copy (local L2)
          stf(&seq_out[t*H + hi], h);   // guaranteed copy (LLC)
        }
        // no barrier: next-iter post-poll barrier orders gates vs dots
      }
      __syncthreads();   // drain before re-staging the next layer's weights
    }
  } else if (lm < NLAYB + NCH) {
    // ======== branch GRU block b (input dim 1, 20 steps) ====================
    const int b = lm - NLAYB;
    const bool act = tid < 480;
    const int rr = tid;                    // full pre-row (under act)
    float* spre = s_buf;        // [320] combined pre (r,z rows)
    float* sxn  = s_buf + 320;  // [160]
    float* shn  = s_buf + 480;  // [160]
    float* sh   = s_buf + 640;  // [160]

    {  // stage whh cols 80..159 quad-major: s_w4[k*481 + r2] = whh[r2][80+4k..]
      const float4* src = (const float4*)(b_whh + (size_t)b*G3*H);
      for (int it = 0; it < 19; ++it){
        int fidx = it*NT + tid;            // r2*20 + k
        if (fidx < 9600){
          int r2 = fidx / 20, k = fidx - r2*20;
          s_w4[k*481 + r2] = src[r2*40 + 20 + k];
        }
      }
    }
    WH_DECL;
    float wij = 0.f, bihj = 0.f, bhhj = 0.f;
    if (act){
      WH_LOAD(b_whh + ((size_t)b*G3 + rr)*H);          // cols 0..79 pinned
      WH_PIN();
      wij  = b_wih[b*G3 + rr];
      bihj = b_bih[b*G3 + rr];
      bhhj = b_bhh[b*G3 + rr];
    }
    if (tid < 160) sh[tid] = 0.f;
    __syncthreads();
    for (int t = 0; t < TCH; ++t){
      float xv = x[b*TCH + t];
      if (act){
        float ahl; WH_DOT80(ahl, sh);
        float ah = bhhj + ahl + dotq20(&s_w4[rr], 481, sh + 80);
        float ax = fmaf(xv, wij, bihj);
        if (rr < 320) spre[rr] = ax + ah;
        else { sxn[rr-320] = ax; shn[rr-320] = ah; }
      }
      __syncthreads();
      if (tid < 160){
        float rg = sigm(spre[tid]);
        float z  = sigm(spre[160 + tid]);
        float n  = tanhf(sxn[tid] + rg * shn[tid]);
        float h  = (1.f - z) * n + z * sh[tid];
        sh[tid] = h;
        if (t == TCH - 1){
          stw(&g_fast[(size_t)b*H + tid], h);           // level 0 chunk b
          stf(&g_seq[(size_t)b*H + tid], h);
        }
      }
      __syncthreads();
    }
  } else {
    // ======== full-x GRU (200 steps) + epilogue =============================
    const bool act = tid < 480;
    const int rr = tid;
    float* spre = s_buf;
    float* sxn  = s_buf + 320;
    float* shn  = s_buf + 480;
    float* sh   = s_buf + 640;

    {
      const float4* src = (const float4*)g_whh;
      for (int it = 0; it < 19; ++it){
        int fidx = it*NT + tid;
        if (fidx < 9600){
          int r2 = fidx / 20, k = fidx - r2*20;
          s_w4[k*481 + r2] = src[r2*40 + 20 + k];
        }
      }
    }
    WH_DECL;
    float wij = 0.f, bihj = 0.f, bhhj = 0.f;
    if (act){
      WH_LOAD(g_whh + (size_t)rr*H);
      WH_PIN();
      wij  = g_wih[rr];
      bihj = g_bih[rr];
      bhhj = g_bhh[rr];
    }
    if (tid < 160) sh[tid] = 0.f;
    __syncthreads();
    float hsum = 0.f;
    for (int t = 0; t < CC; ++t){
      float xv = x[t];
      if (act){
        float ahl; WH_DOT80(ahl, sh);
        float ah = bhhj + ahl + dotq20(&s_w4[rr], 481, sh + 80);
        float ax = fmaf(xv, wij, bihj);
        if (rr < 320) spre[rr] = ax + ah;
        else { sxn[rr-320] = ax; shn[rr-320] = ah; }
      }
      __syncthreads();
      if (tid < 160){
        float rg = sigm(spre[tid]);
        float z  = sigm(spre[160 + tid]);
        float n  = tanhf(sxn[tid] + rg * shn[tid]);
        float h  = (1.f - z) * n + z * sh[tid];
        sh[tid] = h;
        hsum += h;
      }
      __syncthreads();
    }
    // epilogue: poll level-160 h for all chunks, x_cat_l mean+relu, BN, heads
    if (tid < 160){
      float acc = 0.f;
      float* lvl  = g_seq  + (size_t)NLAYERS * NCH * H;
      float* lvlf = g_fast + (size_t)NLAYERS * NCH * H;
      for (int t = 0; t < NCH; ++t) acc += poll2(&lvlf[t*H + tid], &lvl[t*H + tid]);
      float xc   = fmaxf(acc * (1.0f / NCH), 0.f);
      float xl   = hsum * (1.0f / CC);
      float xnew = xl * xc;
      float xbn  = (xnew - bn_mean[tid]) * rsqrtf(bn_var[tid] + 1e-5f)
                   * bn_gamma[tid] + bn_beta[tid];
      spre[tid] = fmaxf(xbn, 0.f);       // xr (reuse s_buf)
    }
    __syncthreads();
    if (tid < NCLS + CC){
      const float* wrow; float acc;
      if (tid < NCLS){ wrow = fc_w + (size_t)tid * H; acc = fc_b[tid]; }
      else           { wrow = reg_w + (size_t)(tid - NCLS) * H; acc = reg_b[tid - NCLS]; }
#pragma unroll
      for (int q = 0; q < 40; q++){
        float4 wv = *(const float4*)(wrow + 4*q);
        f4 xv = *(const f4*)(spre + 4*q);
        acc = fmaf(wv.x, xv.x, acc);
        acc = fmaf(wv.y, xv.y, acc);
        acc = fmaf(wv.z, xv.z, acc);
        acc = fmaf(wv.w, xv.w, acc);
      }
      out[tid] = acc;                    // f32 output: 16 class + 200 rec
    }
  }
}

extern "C" void kernel_launch(void* const* d_in, const int* in_sizes, int n_in,
                              void* d_out, int out_size, void* d_ws, size_t ws_size,
                              hipStream_t stream) {
  (void)in_sizes; (void)n_in; (void)out_size; (void)d_ws; (void)ws_size;

  // re-poison both handoff buffers (stream-ordered before the wave kernel)
  hipLaunchKernelGGL(poison_kernel, dim3((NSEQ + 255)/256), dim3(256), 0, stream);

  hipLaunchKernelGGL(spectral_wave, dim3(GRID), dim3(NT), 0, stream,
    (const float*)d_in[0],
    (const float*)d_in[1],  (const float*)d_in[2],
    (const float*)d_in[3],  (const float*)d_in[4],
    (const float*)d_in[5],  (const float*)d_in[6],
    (const float*)d_in[7],  (const float*)d_in[8],
    (const float*)d_in[9],  (const float*)d_in[10],
    (const float*)d_in[11], (const float*)d_in[12],
    (const float*)d_in[13], (const float*)d_in[14],
    (const float*)d_in[15], (const float*)d_in[16],
    (const float*)d_in[17], (const float*)d_in[18],
    (const float*)d_in[19], (const float*)d_in[20],
    (float*)d_out);
}

// Round 9
// 513.708 us; speedup vs baseline: 1.0823x; 1.0823x over previous
//
#include <hip/hip_runtime.h>
#include <stdint.h>

#define H      160
#define G3     480
#define NCH    10
#define TCH    20
#define CC     200
#define NCLS   16
#define NLAYERS 160
#define NLEVELS 161
#define NSEQ   (NLEVELS * NCH * H)
#define NT     512
#define NPAIR  64
#define NLAYB  (2*NPAIR)          // 128 layer blocks
#define GRID   (NLAYB + NCH + 1)  // 139 blocks, all co-resident on 256 CUs

// Canary: quiet-NaN bit pattern. GRU hidden states are never NaN, so any
// legit value differs. Compare the BIT PATTERN (NaN float-compare is false).
#define CANARY 0x7fbadbadu

typedef float f4 __attribute__((ext_vector_type(4)));

__device__ float g_seq[NSEQ];    // [161][10][160] level/chunk/feature

__device__ __forceinline__ float sigm(float x){ return 1.0f / (1.0f + expf(-x)); }

__device__ __forceinline__ void stf(float* p, float v){      // agent (LLC)
  __hip_atomic_store(p, v, __ATOMIC_RELAXED, __HIP_MEMORY_SCOPE_AGENT);
}
__device__ __forceinline__ float ldf(float* p){              // agent (LLC)
  return __hip_atomic_load(p, __ATOMIC_RELAXED, __HIP_MEMORY_SCOPE_AGENT);
}

// Spin on *p != canary with a VALU burn HIDDEN UNDER the load's flight:
// issue agent-scope load (sc0 sc1 -> LLC), run 64 interleaved v_fmac (two
// independent chains, ~150cy), then waitcnt+check. Purpose: (a) detection
// period stays ~= load RTT (burn is hidden), (b) ~350 polling waves now show
// sustained VALU activity, so the DVFS governor sees a busy chip and holds
// clocks up — the round-8 theory is that mid-state clocks stretch every beat.
// The waitcnt asm takes v as "+v" so the compare is data-dependent on it
// (rule #18: compiler otherwise hoists register-only ops past asm waitcnt).
__device__ __forceinline__ float poll_burn(float* p){
  float v;
  float ba = 1.5f, bb = 2.5f;
  while (true){
    asm volatile("global_load_dword %0, %1, off sc0 sc1"
                 : "=v"(v) : "v"(p) : "memory");
#pragma unroll
    for (int i = 0; i < 32; ++i){
      asm volatile("v_fmac_f32 %0, %1, %1" : "+v"(ba) : "v"(bb));
      asm volatile("v_fmac_f32 %0, %1, %1" : "+v"(bb) : "v"(ba));
    }
    asm volatile("s_waitcnt vmcnt(0)" : "+v"(v) :: "memory");
    if (__float_as_uint(v) != CANARY) break;
  }
  asm volatile("" :: "v"(ba), "v"(bb));   // keep the burn live
  return v;
}

// 80-MAC dot with weights in quad-column-major LDS: w[k*stride] for k=0..19.
// Lane-to-lane stride = 1 float4 -> conflict-free reads.
__device__ __forceinline__ float dotq20(const float4* __restrict__ w, int stride,
                                        const float* __restrict__ v){
  float a0 = 0.f, a1 = 0.f;
#pragma unroll
  for (int k = 0; k < 20; k += 2){
    float4 wa = w[k*stride], wb = w[(k+1)*stride];
    f4 va = *(const f4*)(v + 4*k), vb = *(const f4*)(v + 4*k + 4);
    a0 = fmaf(wa.x, va.x, a0); a0 = fmaf(wa.y, va.y, a0);
    a0 = fmaf(wa.z, va.z, a0); a0 = fmaf(wa.w, va.w, a0);
    a1 = fmaf(wb.x, vb.x, a1); a1 = fmaf(wb.y, vb.y, a1);
    a1 = fmaf(wb.z, vb.z, a1); a1 = fmaf(wb.w, vb.w, a1);
  }
  return a0 + a1;
}

// ---- 80 columns of whh pinned in 20 named VGPR quads (80 VGPRs) -----------
#define WH_DECL  f4 w00,w01,w02,w03,w04,w05,w06,w07,w08,w09, \
                    w10,w11,w12,w13,w14,w15,w16,w17,w18,w19
#define WH_LOAD(SRC) do { const f4* ws_ = (const f4*)(SRC); \
  w00=ws_[0]; w01=ws_[1]; w02=ws_[2]; w03=ws_[3]; w04=ws_[4]; \
  w05=ws_[5]; w06=ws_[6]; w07=ws_[7]; w08=ws_[8]; w09=ws_[9]; \
  w10=ws_[10];w11=ws_[11];w12=ws_[12];w13=ws_[13];w14=ws_[14]; \
  w15=ws_[15];w16=ws_[16];w17=ws_[17];w18=ws_[18];w19=ws_[19]; } while(0)
#define WH_PIN() asm volatile("" : \
  "+v"(w00),"+v"(w01),"+v"(w02),"+v"(w03),"+v"(w04), \
  "+v"(w05),"+v"(w06),"+v"(w07),"+v"(w08),"+v"(w09), \
  "+v"(w10),"+v"(w11),"+v"(w12),"+v"(w13),"+v"(w14), \
  "+v"(w15),"+v"(w16),"+v"(w17),"+v"(w18),"+v"(w19))
#define MACP(WA,WB,OFF) do { \
  f4 va_ = *(const f4*)(v_ + (OFF));  f4 vb_ = *(const f4*)(v_ + (OFF) + 4); \
  a0_=fmaf(WA.x,va_.x,a0_); a0_=fmaf(WA.y,va_.y,a0_); \
  a0_=fmaf(WA.z,va_.z,a0_); a0_=fmaf(WA.w,va_.w,a0_); \
  a1_=fmaf(WB.x,vb_.x,a1_); a1_=fmaf(WB.y,vb_.y,a1_); \
  a1_=fmaf(WB.z,vb_.z,a1_); a1_=fmaf(WB.w,vb_.w,a1_); } while(0)
#define WH_DOT80(RES, VBASE) do { const float* v_ = (VBASE); \
  float a0_=0.f, a1_=0.f; \
  MACP(w00,w01,0);  MACP(w02,w03,8);  MACP(w04,w05,16); MACP(w06,w07,24); \
  MACP(w08,w09,32); MACP(w10,w11,40); MACP(w12,w13,48); MACP(w14,w15,56); \
  MACP(w16,w17,64); MACP(w18,w19,72); (RES) = a0_ + a1_; } while(0)
// ---------------------------------------------------------------------------

extern "C" __global__ void poison_kernel(){
  int i = threadIdx.x + blockIdx.x * blockDim.x;
  if (i < NSEQ) stf(&g_seq[i], __uint_as_float(CANARY));
}

extern "C" __global__ __launch_bounds__(NT, 1)
void spectral_wave(
  const float* __restrict__ x,
  const float* __restrict__ b_wih, const float* __restrict__ b_whh,
  const float* __restrict__ b_bih, const float* __restrict__ b_bhh,
  const float* __restrict__ g_wih, const float* __restrict__ g_whh,
  const float* __restrict__ g_bih, const float* __restrict__ g_bhh,
  const float* __restrict__ g3_wih, const float* __restrict__ g3_whh,
  const float* __restrict__ g3_bih, const float* __restrict__ g3_bhh,
  const float* __restrict__ bn_gamma, const float* __restrict__ bn_beta,
  const float* __restrict__ bn_mean,  const float* __restrict__ bn_var,
  const float* __restrict__ fc_w, const float* __restrict__ fc_b,
  const float* __restrict__ reg_w, const float* __restrict__ reg_b,
  float* __restrict__ out)
{
  const int tid = threadIdx.x;
  const int bid = blockIdx.x;

  // 9640 float4 = 154.2 KB weight LDS + 5.1 KB buffers = 159.4 KB (<160 KiB)
  // Pitch 241/481: staging writes conflict-free (round-8 verified: 2.77M->131K)
  __shared__ float4 s_w4[9640];
  __shared__ __align__(16) float s_buf[1280];

  if (bid < NLAYB) {
    // ======== layer-half block: pair p, role (A: h 0..79 / B: h 80..159) ====
    const int p = bid >> 1, role = bid & 1, hbase = role * 80;
    const int nlay = (p < 32) ? 3 : 2;     // layers p, p+64, (p+128 if p<32)
    const bool act = tid < 480;
    const int j    = tid % 240;            // local pre-row 0..239
    // K-half remap (round-9): pollers (tid<240) take the SIBLING h-half
    // (they must wait for it anyway); tid 240-479 take the OWN half, whose
    // h is locally produced -> their whh partial runs DURING the poll phase.
    const int hf   = act ? ((tid < 240) ? (1 - role) : role) : 0;
    const int c0   = 80 * hf;
    const int band = j / 80;               // 0=r rows,1=z rows,2=n rows
    const int grow = band*160 + (j % 80) + hbase;  // global pre-row 0..479

    float* sx   = s_buf;        // [160] input chunk
    float* sh   = s_buf + 160;  // [160] recurrent h (own half + polled half)
    float* swp  = s_buf + 320;  // [2][240] per-half partials
    float* shp2 = s_buf + 800;  // [2][80]  band-2 h-partials (hn)

    for (int li = 0; li < nlay; ++li){
      const int l = p + 64*li;

      // stage wih half (rows grow(j), all 160 cols) quad-column-major:
      // s_w4[qi*241 + jj] = wih[grow(jj)][4qi..4qi+3]
      {
        const float4* src = (const float4*)(g3_wih + (size_t)l*G3*H);
        for (int it = 0; it < 19; ++it){
          int fidx = it*NT + tid;            // jj*40 + qi
          if (fidx < 9600){
            int jj = fidx / 40, qi = fidx - jj*40;
            int gr = (jj/80)*160 + (jj%80) + hbase;
            s_w4[qi*241 + jj] = src[gr*40 + qi];
          }
        }
      }
      WH_DECL;
      float bihj = 0.f, bhhj = 0.f;
      if (act){
        WH_LOAD(g3_whh + ((size_t)l*G3 + grow)*H + c0);
        WH_PIN();
        if (hf == 0){ bihj = g3_bih[l*G3 + grow]; bhhj = g3_bhh[l*G3 + grow]; }
      }
      if (tid < 160) sh[tid] = 0.f;
      __syncthreads();

      float* seq_in  = g_seq + (size_t)l     * NCH * H;
      float* seq_out = g_seq + (size_t)(l+1) * NCH * H;

      for (int t = 0; t < NCH; ++t){
        // ---- phase 1: early own-half whh dot (tid>=240) || polls (tid<240)
        float s_h = 0.f;
        if (act && tid >= 240){ WH_DOT80(s_h, sh + c0); s_h += bhhj; }
        if (tid < 160){
          sx[tid] = poll_burn(&seq_in[t*H + tid]);       // poll IS the load
        } else if (tid < 240 && t > 0){
          int oi = (role == 0 ? 80 : 0) + (tid - 160);   // sibling h half
          sh[oi] = poll_burn(&seq_out[(t-1)*H + oi]);
        }
        __syncthreads();
        // ---- phase 2: remaining dots
        if (act){
          if (tid < 240){ WH_DOT80(s_h, sh + c0); s_h += bhhj; }
          float s_w = dotq20(&s_w4[hf*4820 + j], 241, sx + c0) + bihj;
          if (band < 2) swp[hf*240 + j] = s_w + s_h;
          else { swp[hf*240 + j] = s_w; shp2[hf*80 + (j-160)] = s_h; }
        }
        __syncthreads();
        // ---- gates
        if (tid < 80){
          int i = tid, hi = hbase + i;
          float pr = swp[i]       + swp[240 + i];
          float pz = swp[80 + i]  + swp[320 + i];
          float xn = swp[160 + i] + swp[400 + i];
          float hn = shp2[i]      + shp2[80 + i];
          float rg = sigm(pr);
          float z  = sigm(pz);
          float n  = tanhf(xn + rg * hn);
          float h  = (1.f - z) * n + z * sh[hi];
          sh[hi] = h;
          stf(&seq_out[t*H + hi], h);   // the only cross-block hop per beat
        }
        __syncthreads();   // gate-barrier: orders sh writes before phase-1 reads
      }
      // (loop-final gate-barrier also orders before next layer's re-stage)
    }
  } else if (bid < NLAYB + NCH) {
    // ======== branch GRU block b (input dim 1, 20 steps) ====================
    const int b = bid - NLAYB;
    const bool act = tid < 480;
    const int rr = tid;                    // full pre-row (under act)
    float* spre = s_buf;        // [320] combined pre (r,z rows)
    float* sxn  = s_buf + 320;  // [160]
    float* shn  = s_buf + 480;  // [160]
    float* sh   = s_buf + 640;  // [160]

    {  // stage whh cols 80..159 quad-major: s_w4[k*481 + r2] = whh[r2][80+4k..]
      const float4* src = (const float4*)(b_whh + (size_t)b*G3*H);
      for (int it = 0; it < 19; ++it){
        int fidx = it*NT + tid;            // r2*20 + k
        if (fidx < 9600){
          int r2 = fidx / 20, k = fidx - r2*20;
          s_w4[k*481 + r2] = src[r2*40 + 20 + k];
        }
      }
    }
    WH_DECL;
    float wij = 0.f, bihj = 0.f, bhhj = 0.f;
    if (act){
      WH_LOAD(b_whh + ((size_t)b*G3 + rr)*H);          // cols 0..79 pinned
      WH_PIN();
      wij  = b_wih[b*G3 + rr];
      bihj = b_bih[b*G3 + rr];
      bhhj = b_bhh[b*G3 + rr];
    }
    if (tid < 160) sh[tid] = 0.f;
    __syncthreads();
    for (int t = 0; t < TCH; ++t){
      float xv = x[b*TCH + t];
      if (act){
        float ahl; WH_DOT80(ahl, sh);
        float ah = bhhj + ahl + dotq20(&s_w4[rr], 481, sh + 80);
        float ax = fmaf(xv, wij, bihj);
        if (rr < 320) spre[rr] = ax + ah;
        else { sxn[rr-320] = ax; shn[rr-320] = ah; }
      }
      __syncthreads();
      if (tid < 160){
        float rg = sigm(spre[tid]);
        float z  = sigm(spre[160 + tid]);
        float n  = tanhf(sxn[tid] + rg * shn[tid]);
        float h  = (1.f - z) * n + z * sh[tid];
        sh[tid] = h;
        if (t == TCH - 1) stf(&g_seq[(size_t)b*H + tid], h);  // level 0 chunk b
      }
      __syncthreads();
    }
  } else {
    // ======== full-x GRU (200 steps) + epilogue =============================
    const bool act = tid < 480;
    const int rr = tid;
    float* spre = s_buf;
    float* sxn  = s_buf + 320;
    float* shn  = s_buf + 480;
    float* sh   = s_buf + 640;

    {
      const float4* src = (const float4*)g_whh;
      for (int it = 0; it < 19; ++it){
        int fidx = it*NT + tid;
        if (fidx < 9600){
          int r2 = fidx / 20, k = fidx - r2*20;
          s_w4[k*481 + r2] = src[r2*40 + 20 + k];
        }
      }
    }
    WH_DECL;
    float wij = 0.f, bihj = 0.f, bhhj = 0.f;
    if (act){
      WH_LOAD(g_whh + (size_t)rr*H);
      WH_PIN();
      wij  = g_wih[rr];
      bihj = g_bih[rr];
      bhhj = g_bhh[rr];
    }
    if (tid < 160) sh[tid] = 0.f;
    __syncthreads();
    float hsum = 0.f;
    for (int t = 0; t < CC; ++t){
      float xv = x[t];
      if (act){
        float ahl; WH_DOT80(ahl, sh);
        float ah = bhhj + ahl + dotq20(&s_w4[rr], 481, sh + 80);
        float ax = fmaf(xv, wij, bihj);
        if (rr < 320) spre[rr] = ax + ah;
        else { sxn[rr-320] = ax; shn[rr-320] = ah; }
      }
      __syncthreads();
      if (tid < 160){
        float rg = sigm(spre[tid]);
        float z  = sigm(spre[160 + tid]);
        float n  = tanhf(sxn[tid] + rg * shn[tid]);
        float h  = (1.f - z) * n + z * sh[tid];
        sh[tid] = h;
        hsum += h;
      }
      __syncthreads();
    }
    // epilogue: poll level-160 h for all chunks, x_cat_l mean+relu, BN, heads
    if (tid < 160){
      float acc = 0.f;
      float* lvl = g_seq + (size_t)NLAYERS * NCH * H;
      for (int t = 0; t < NCH; ++t) acc += poll_burn(&lvl[t*H + tid]);
      float xc   = fmaxf(acc * (1.0f / NCH), 0.f);
      float xl   = hsum * (1.0f / CC);
      float xnew = xl * xc;
      float xbn  = (xnew - bn_mean[tid]) * rsqrtf(bn_var[tid] + 1e-5f)
                   * bn_gamma[tid] + bn_beta[tid];
      spre[tid] = fmaxf(xbn, 0.f);       // xr (reuse s_buf)
    }
    __syncthreads();
    if (tid < NCLS + CC){
      const float* wrow; float acc;
      if (tid < NCLS){ wrow = fc_w + (size_t)tid * H; acc = fc_b[tid]; }
      else           { wrow = reg_w + (size_t)(tid - NCLS) * H; acc = reg_b[tid - NCLS]; }
#pragma unroll
      for (int q = 0; q < 40; q++){
        float4 wv = *(const float4*)(wrow + 4*q);
        f4 xv = *(const f4*)(spre + 4*q);
        acc = fmaf(wv.x, xv.x, acc);
        acc = fmaf(wv.y, xv.y, acc);
        acc = fmaf(wv.z, xv.z, acc);
        acc = fmaf(wv.w, xv.w, acc);
      }
      out[tid] = acc;                    // f32 output: 16 class + 200 rec
    }
  }
}

extern "C" void kernel_launch(void* const* d_in, const int* in_sizes, int n_in,
                              void* d_out, int out_size, void* d_ws, size_t ws_size,
                              hipStream_t stream) {
  (void)in_sizes; (void)n_in; (void)out_size; (void)d_ws; (void)ws_size;

  // re-poison the handoff buffer (stream-ordered before the wave kernel)
  hipLaunchKernelGGL(poison_kernel, dim3((NSEQ + 255)/256), dim3(256), 0, stream);

  hipLaunchKernelGGL(spectral_wave, dim3(GRID), dim3(NT), 0, stream,
    (const float*)d_in[0],
    (const float*)d_in[1],  (const float*)d_in[2],
    (const float*)d_in[3],  (const float*)d_in[4],
    (const float*)d_in[5],  (const float*)d_in[6],
    (const float*)d_in[7],  (const float*)d_in[8],
    (const float*)d_in[9],  (const float*)d_in[10],
    (const float*)d_in[11], (const float*)d_in[12],
    (const float*)d_in[13], (const float*)d_in[14],
    (const float*)d_in[15], (const float*)d_in[16],
    (const float*)d_in[17], (const float*)d_in[18],
    (const float*)d_in[19], (const float*)d_in[20],
    (float*)d_out);
}